// Round 8
// baseline (209.054 us; speedup 1.0000x reference)
//
#include <hip/hip_runtime.h>

// InterestTransformerDecoder: B=512, L=L1=256, D=128.
// Inputs f32: d_in[0]=seq i32, [1]=last i32, [2]=seq1 i32,
// [3]=hist_1 f32[512*256*128], [4]=hist_2 f32, [5]=W f32[128*128].
// Output f32[512*128].
// R4 209us / R5 204us verified (98us/dispatch). R6-R10 split: regressed
// (spills). R11 (16 waves, Occ 20->40%): dispatch STILL 98us -> occupancy is
// NOT the limiter; the per-jt serial LDS chain (K rd -> MFMA -> exp -> WST
// u16 scatter [4-way bank conflict, 8.45M cycles] -> fence -> WST rd -> PV
// MFMA -> T rd -> transpose-shuffle stage) x 16-wave lockstep barriers is.
// R12: ALGORITHM change. h_self is only used pooled by last:
//   h_pool[d] = sum_j cfull[j]*h1[j,d],  cfull[j] = m[j]*c[j] + LM[j],
//   c[j] = sum_i (LM[i]/wsum[i]) * exp(cos_ij).
// Two streaming passes over j-tiles (pass1: wsum[i]; pass2: c[j] via
// 2-shuffle reduce + LDS atomicAdd). DELETED: PV GEMM, Tbuf staging+reads,
// WST roundtrip, threadfence, acc[8] (32 VGPR). Same total MFMA count.
// Final pool = one coalesced f32 sweep of h1. Cross attn + W GEMM unchanged
// (R11-verified). LDS 38.4KB; ~60 VGPR -> 2 blocks/CU.
// Predict: bank conflicts <2M, dispatch 98 -> 45-65us.

using u16 = unsigned short;
using u32 = unsigned int;
typedef __attribute__((ext_vector_type(8))) short bf16x8;
typedef __attribute__((ext_vector_type(4))) float f32x4;
typedef __attribute__((ext_vector_type(4))) u32 u32x4;

#define KST 136   // Kbuf row stride (u16): 128 data + 8 pad (272B = 17x16 ok)
#define KBSZ 4352 // u16 per K tile buffer (32*KST)

__device__ __forceinline__ u16 f2bf(float f) {
  union { float f; u32 i; } v; v.f = f;
  u32 r = v.i + 0x7FFFu + ((v.i >> 16) & 1u);   // RNE
  return (u16)(r >> 16);
}
__device__ __forceinline__ bf16x8 as_bf(u32x4 x) {
  union { u32x4 u; bf16x8 b; } c; c.u = x; return c.b;
}
__device__ __forceinline__ u32x4 packpair(float4 a, float4 c) {
  u32x4 v;
  v.x = (u32)f2bf(a.x) | ((u32)f2bf(a.y) << 16);
  v.y = (u32)f2bf(a.z) | ((u32)f2bf(a.w) << 16);
  v.z = (u32)f2bf(c.x) | ((u32)f2bf(c.y) << 16);
  v.w = (u32)f2bf(c.z) | ((u32)f2bf(c.w) << 16);
  return v;
}
__device__ __forceinline__ u32x4 pack_bf8(const float* p, float& ss) {
  const float4 a = *(const float4*)p;
  const float4 c = *(const float4*)(p + 4);
  ss += a.x*a.x + a.y*a.y + a.z*a.z + a.w*a.w
      + c.x*c.x + c.y*c.y + c.z*c.z + c.w*c.w;
  return packpair(a, c);
}

// Stage one row (8 bf16 in v; lane covers cols m16*8..+7) of a 32-row K tile
// + per-row inv-norm. Stager waves wv=0..7 cover rows wv*4+q. (No transpose
// buffer anymore -- PV GEMM is gone.)
__device__ __forceinline__ void stage_k(u32x4 v, float ss, u16* kb,
                                        float* invt, int wv, int q, int m16) {
  const int row = wv * 4 + q;            // tile-local row 0..31
  *(u32x4*)&kb[row * KST + m16 * 8] = v;
  ss += __shfl_xor(ss, 1); ss += __shfl_xor(ss, 2);
  ss += __shfl_xor(ss, 4); ss += __shfl_xor(ss, 8);
  if (m16 == 0) invt[row] = rsqrtf(ss + 0.01f);
}

__launch_bounds__(1024, 4)
__global__ void itd_fused(const int* __restrict__ seq,
                          const int* __restrict__ lastseq,
                          const int* __restrict__ seq1,
                          const float* __restrict__ h1g,
                          const float* __restrict__ h2g,
                          const float* __restrict__ wg,
                          float* __restrict__ outg) {
  // SBIG: Kb dbuf (17,408 B) during attention; PSC f32[64][132] (33,792 B)
  // for the pooling sweeps / cross attn after the loop (Kb dead by then).
  __shared__ unsigned long long SBIG[4224];      // 33,792 B
  __shared__ float MK[256], LM[256], CJ[256], HLacc[128], HH[128];
  __shared__ float INVT[2][32], WS2[64], SC[2];

  u16* const Kb    = (u16*)SBIG;                 // + cur*KBSZ
  float* const PSC = (float*)SBIG;               // post-loop f32 scratch

  const int b    = blockIdx.x;
  const int t    = threadIdx.x;
  const int lane = t & 63;
  const int wv   = t >> 6;                       // 0..15
  const int q    = lane >> 4;
  const int m16  = lane & 15;

  const float* h1b = h1g + (size_t)b * 32768;

  if (t < 256) {
    float m = (seq[b * 256 + t] != 0) ? 1.f : 0.f;
    MK[t] = m;
    LM[t] = m * (float)lastseq[b * 256 + t];
    CJ[t] = 0.f;
  }

  // ---- Q fragments: wave wv owns query rows i0..i0+15 ----
  const int i0 = wv * 16;
  u32x4 av[4];
  float invi[4];
  {
    float ss = 0.f;
    #pragma unroll
    for (int s = 0; s < 4; ++s)
      av[s] = pack_bf8(&h1b[(i0 + m16) * 128 + s * 32 + q * 8], ss);
    ss += __shfl_xor(ss, 16);
    ss += __shfl_xor(ss, 32);
    const float invrow = rsqrtf(ss + 0.01f);     // lane holds row i0+m16's inv
    #pragma unroll
    for (int r = 0; r < 4; ++r) invi[r] = __shfl(invrow, q * 4 + r);
  }

  // staging slots (t<512): row srow = wv*4+q (0..31), cols scol..scol+7
  const int srow = wv * 4 + q;
  const int scol = m16 * 8;
  if (t < 512) {
    const float4 a0 = *(const float4*)&h1b[srow * 128 + scol];
    const float4 c0 = *(const float4*)&h1b[srow * 128 + scol + 4];
    float ss = a0.x*a0.x + a0.y*a0.y + a0.z*a0.z + a0.w*a0.w
             + c0.x*c0.x + c0.y*c0.y + c0.z*c0.z + c0.w*c0.w;
    stage_k(packpair(a0, c0), ss, Kb, INVT[0], wv, q, m16);
  }
  __syncthreads();   // masks, CJ=0, tile0 visible

  // ---- two streaming passes: jt 0..7 = wsum, jt 8..15 = c[j] ----
  const f32x4 fz = {0.f, 0.f, 0.f, 0.f};
  float wpart[4] = {0.f, 0.f, 0.f, 0.f};
  float coef[4];

  for (int jt = 0; jt < 16; ++jt) {
    const int cur  = jt & 1;
    const int tile = jt & 7;
    float4 pfa, pfb;
    if (t < 512 && jt < 15) {                    // prefetch next tile (8 f32)
      const float* np = &h1b[((jt + 1) & 7) * 4096 + srow * 128 + scol];
      pfa = *(const float4*)np;
      pfb = *(const float4*)(np + 4);
    }

    // S = Q.K^T: 16 queries x 32 keys
    f32x4 Sa = fz, Sb = fz;
    const u16* kb = Kb + cur * KBSZ;
    #pragma unroll
    for (int s = 0; s < 4; ++s) {
      bf16x8 ba = *(const bf16x8*)&kb[m16 * KST + s * 32 + q * 8];
      bf16x8 bb = *(const bf16x8*)&kb[(16 + m16) * KST + s * 32 + q * 8];
      bf16x8 af = as_bf(av[s]);
      Sa = __builtin_amdgcn_mfma_f32_16x16x32_bf16(af, ba, Sa, 0, 0, 0);
      Sb = __builtin_amdgcn_mfma_f32_16x16x32_bf16(af, bb, Sb, 0, 0, 0);
    }
    const float invja = INVT[cur][m16];
    const float invjb = INVT[cur][16 + m16];
    if (jt < 8) {
      // pass 1: wsum[i] partials (mask on keys included)
      const float mja = MK[tile * 32 + m16];
      const float mjb = MK[tile * 32 + 16 + m16];
      #pragma unroll
      for (int r = 0; r < 4; ++r) {
        wpart[r] += __expf(Sa[r] * (invi[r] * invja)) * mja
                  + __expf(Sb[r] * (invi[r] * invjb)) * mjb;
      }
      if (jt == 7) {                             // wsum complete -> coef
        #pragma unroll
        for (int r = 0; r < 4; ++r) {
          float s = wpart[r];
          s += __shfl_xor(s, 1); s += __shfl_xor(s, 2);
          s += __shfl_xor(s, 4); s += __shfl_xor(s, 8);
          coef[r] = LM[i0 + q * 4 + r] / s;
        }
      }
    } else {
      // pass 2: c[j] += coef_i * exp(cos_ij)  (key mask applied later)
      float ca = 0.f, cb = 0.f;
      #pragma unroll
      for (int r = 0; r < 4; ++r) {
        ca += coef[r] * __expf(Sa[r] * (invi[r] * invja));
        cb += coef[r] * __expf(Sb[r] * (invi[r] * invjb));
      }
      ca += __shfl_xor(ca, 16); ca += __shfl_xor(ca, 32);
      cb += __shfl_xor(cb, 16); cb += __shfl_xor(cb, 32);
      if (q == 0) {
        atomicAdd(&CJ[tile * 32 + m16], ca);
        atomicAdd(&CJ[tile * 32 + 16 + m16], cb);
      }
    }

    if (t < 512 && jt < 15) {                    // stage next tile
      float ss = pfa.x*pfa.x + pfa.y*pfa.y + pfa.z*pfa.z + pfa.w*pfa.w
               + pfb.x*pfb.x + pfb.y*pfb.y + pfb.z*pfb.z + pfb.w*pfb.w;
      stage_k(packpair(pfa, pfb), ss, Kb + (cur ^ 1) * KBSZ,
              INVT[cur ^ 1], wv, q, m16);
    }
    __syncthreads();
  }

  // ---- cfull[j] = m[j]*c[j] + LM[j] (residual folded in) ----
  if (t < 256) CJ[t] = MK[t] * CJ[t] + LM[t];
  __syncthreads();

  // ---- pooled sweep: HL[d] = sum_j cfull[j]*h1[j,d] (coalesced f32) ----
  {
    const int g = t >> 7, dd = t & 127;          // 8 groups x 32 rows
    float p = 0.f;
    #pragma unroll 8
    for (int n = 0; n < 32; ++n)
      p += CJ[g * 32 + n] * h1b[(g * 32 + n) * 128 + dd];
    PSC[g * 132 + dd] = p;
  }
  __syncthreads();
  if (t < 128) {
    float s = 0.f;
    #pragma unroll
    for (int g = 0; g < 8; ++g) s += PSC[g * 132 + t];
    HLacc[t] = s;
  }
  __syncthreads();

  // ---- cross cosine attention over h2 (single pass, t<512) ----
  if (t < 64) {
    float s = HLacc[t] * HLacc[t] + HLacc[t + 64] * HLacc[t + 64];
    s += __shfl_xor(s, 1); s += __shfl_xor(s, 2); s += __shfl_xor(s, 4);
    s += __shfl_xor(s, 8); s += __shfl_xor(s, 16); s += __shfl_xor(s, 32);
    if (t == 0) SC[0] = rsqrtf(s + 0.01f);
  }
  if (t < 256) MK[t] = (seq1[b * 256 + t] != 0) ? 1.f : 0.f;
  __syncthreads();

  const float* h2b = h2g + (size_t)b * 32768;
  if (t < 512) {
    const int row8 = lane >> 3;          // 0..7
    const int sub  = lane & 7;           // 8 lanes/row, 16 f32 each
    const int slot = wv * 8 + row8;      // 0..63
    const float invq = SC[0];
    f32x4 acc4[4];
    #pragma unroll
    for (int c = 0; c < 4; ++c) acc4[c] = {0.f, 0.f, 0.f, 0.f};
    float ws2 = 0.f;
    const float* hl = &HLacc[sub * 4];
    #pragma unroll
    for (int kt = 0; kt < 4; ++kt) {
      const int k = kt * 64 + slot;
      const float* rowp = h2b + k * 128 + sub * 4;
      const float4 v0 = *(const float4*)(rowp);
      const float4 v1 = *(const float4*)(rowp + 32);
      const float4 v2 = *(const float4*)(rowp + 64);
      const float4 v3 = *(const float4*)(rowp + 96);
      float dot = v0.x*hl[0]  + v0.y*hl[1]  + v0.z*hl[2]  + v0.w*hl[3]
                + v1.x*hl[32] + v1.y*hl[33] + v1.z*hl[34] + v1.w*hl[35]
                + v2.x*hl[64] + v2.y*hl[65] + v2.z*hl[66] + v2.w*hl[67]
                + v3.x*hl[96] + v3.y*hl[97] + v3.z*hl[98] + v3.w*hl[99];
      float ss  = v0.x*v0.x + v0.y*v0.y + v0.z*v0.z + v0.w*v0.w
                + v1.x*v1.x + v1.y*v1.y + v1.z*v1.z + v1.w*v1.w
                + v2.x*v2.x + v2.y*v2.y + v2.z*v2.z + v2.w*v2.w
                + v3.x*v3.x + v3.y*v3.y + v3.z*v3.z + v3.w*v3.w;
      dot += __shfl_xor(dot, 1); dot += __shfl_xor(dot, 2); dot += __shfl_xor(dot, 4);
      ss  += __shfl_xor(ss, 1);  ss  += __shfl_xor(ss, 2);  ss  += __shfl_xor(ss, 4);
      const float w2 = __expf(dot * rsqrtf(ss + 0.01f) * invq) * MK[k];
      ws2 += w2;
      acc4[0][0] += w2*v0.x; acc4[0][1] += w2*v0.y; acc4[0][2] += w2*v0.z; acc4[0][3] += w2*v0.w;
      acc4[1][0] += w2*v1.x; acc4[1][1] += w2*v1.y; acc4[1][2] += w2*v1.z; acc4[1][3] += w2*v1.w;
      acc4[2][0] += w2*v2.x; acc4[2][1] += w2*v2.y; acc4[2][2] += w2*v2.z; acc4[2][3] += w2*v2.w;
      acc4[3][0] += w2*v3.x; acc4[3][1] += w2*v3.y; acc4[3][2] += w2*v3.z; acc4[3][3] += w2*v3.w;
    }
    #pragma unroll
    for (int c = 0; c < 4; ++c)
      *(f32x4*)&PSC[slot * 132 + c * 32 + sub * 4] = acc4[c];
    if (sub == 0) WS2[slot] = ws2;
  }
  __syncthreads();

  float hsum = 0.f;
  if (t < 128) {
    #pragma unroll
    for (int n = 0; n < 64; ++n) hsum += PSC[n * 132 + t];
  }
  if (t < 64) {
    float s = WS2[t];
    s += __shfl_xor(s, 1); s += __shfl_xor(s, 2); s += __shfl_xor(s, 4);
    s += __shfl_xor(s, 8); s += __shfl_xor(s, 16); s += __shfl_xor(s, 32);
    if (t == 0) SC[1] = s;
  }
  __syncthreads();
  if (t < 128) HH[t] = hsum / SC[1];
  __syncthreads();

  if (t < 128) {
    float o = 0.f;
    #pragma unroll 8
    for (int d = 0; d < 128; ++d)
      o += HH[d] * wg[d * 128 + t];
    outg[(size_t)b * 128 + t] = fmaxf(o, 0.f);
  }
}

extern "C" void kernel_launch(void* const* d_in, const int* in_sizes, int n_in,
                              void* d_out, int out_size, void* d_ws, size_t ws_size,
                              hipStream_t stream) {
  (void)in_sizes; (void)n_in; (void)d_ws; (void)ws_size; (void)out_size;
  const int*   seq     = (const int*)d_in[0];
  const int*   lastseq = (const int*)d_in[1];
  const int*   seq1    = (const int*)d_in[2];
  const float* h1      = (const float*)d_in[3];
  const float* h2      = (const float*)d_in[4];
  const float* w       = (const float*)d_in[5];
  float* out           = (float*)d_out;
  itd_fused<<<dim3(512), dim3(1024), 0, stream>>>(seq, lastseq, seq1, h1, h2, w, out);
}

// Round 9
// 203.760 us; speedup vs baseline: 1.0260x; 1.0260x over previous
//
#include <hip/hip_runtime.h>

// InterestTransformerDecoder: B=512, L=L1=256, D=128.
// Inputs f32: d_in[0]=seq i32, [1]=last i32, [2]=seq1 i32,
// [3]=hist_1 f32[512*256*128], [4]=hist_2 f32, [5]=W f32[128*128].
// Output f32[512*128].
// History: R4 209us / R5 204us verified (98us/disp). R6-R10 split: spills,
// regressed. R11 16-wave (Occ 40%): 98us unchanged. R12 c[j]-reformulation
// (PV GEMM + WST roundtrip + Tbuf DELETED, QK^T doubled): 102us unchanged,
// conflicts 8.45M->4.19M, VALU 28%. CONCLUSION: limiter is phase-lockstep --
// a barrier every ~800cy re-aligns all waves, so DS/VALU/trans bursts never
// overlap across waves (sum-of-pipes ~30us vs wall 102us).
// R13: (a) stage 128-row K half (32KB, XOR-swizzle (row&7)<<4 -> conflict-
// free b128 reads), each wave then sweeps 4 tiles BARRIER-FREE (desync
// window ~3-4k cy); 9 barriers total vs 16. (b) 8 waves x 32 queries/wave:
// K LDS-read traffic halved (DS floor ~20->11us). (c) key mask folded into
// exp bias (scale_j=0,bias_j=-1e38) -- no MK read/mul in loop. Staging not
// overlapped (4x ~0.4us, accepted). Predict: conflicts <1M, disp 55-75us.

using u16 = unsigned short;
using u32 = unsigned int;
typedef __attribute__((ext_vector_type(8))) short bf16x8;
typedef __attribute__((ext_vector_type(4))) float f32x4;
typedef __attribute__((ext_vector_type(4))) u32 u32x4;

__device__ __forceinline__ u16 f2bf(float f) {
  union { float f; u32 i; } v; v.f = f;
  u32 r = v.i + 0x7FFFu + ((v.i >> 16) & 1u);   // RNE
  return (u16)(r >> 16);
}
__device__ __forceinline__ bf16x8 as_bf(u32x4 x) {
  union { u32x4 u; bf16x8 b; } c; c.u = x; return c.b;
}
__device__ __forceinline__ u32x4 packpair(float4 a, float4 c) {
  u32x4 v;
  v.x = (u32)f2bf(a.x) | ((u32)f2bf(a.y) << 16);
  v.y = (u32)f2bf(a.z) | ((u32)f2bf(a.w) << 16);
  v.z = (u32)f2bf(c.x) | ((u32)f2bf(c.y) << 16);
  v.w = (u32)f2bf(c.z) | ((u32)f2bf(c.w) << 16);
  return v;
}
__device__ __forceinline__ u32x4 pack_bf8(const float* p, float& ss) {
  const float4 a = *(const float4*)p;
  const float4 c = *(const float4*)(p + 4);
  ss += a.x*a.x + a.y*a.y + a.z*a.z + a.w*a.w
      + c.x*c.x + c.y*c.y + c.z*c.z + c.w*c.w;
  return packpair(a, c);
}

__launch_bounds__(512)
__global__ void itd_fused(const int* __restrict__ seq,
                          const int* __restrict__ lastseq,
                          const int* __restrict__ seq1,
                          const float* __restrict__ h1g,
                          const float* __restrict__ h2g,
                          const float* __restrict__ wg,
                          float* __restrict__ outg) {
  // SBIG: KS = 128x128 bf16 swizzled K-half (32,768 B) during attention;
  // PSC f32 scratch (pool 4x132, cross 64x132 = 33,792 B) after (KS dead).
  __shared__ unsigned long long SBIG[4224];      // 33,792 B
  __shared__ float MK[256], LM[256], CJ[256];
  __shared__ float SCL[128], SBS[128];           // per-row scale / bias (half)
  __shared__ float HLacc[128], HH[128], WS2[64], SC[2];

  u16* const   KS  = (u16*)SBIG;
  float* const PSC = (float*)SBIG;

  const int b    = blockIdx.x;
  const int t    = threadIdx.x;
  const int lane = t & 63;
  const int wv   = t >> 6;                       // 0..7
  const int q    = lane >> 4;
  const int m16  = lane & 15;

  const float* h1b = h1g + (size_t)b * 32768;

  if (t < 256) {
    float m = (seq[b * 256 + t] != 0) ? 1.f : 0.f;
    MK[t] = m;
    LM[t] = m * (float)lastseq[b * 256 + t];
    CJ[t] = 0.f;
  }

  // ---- Q fragments: wave wv owns query rows wv*32 .. wv*32+31 ----
  u32x4 av[2][4];
  float invi[2][4];
  #pragma unroll
  for (int rt = 0; rt < 2; ++rt) {
    const int i0q = wv * 32 + rt * 16;
    float ss = 0.f;
    #pragma unroll
    for (int s = 0; s < 4; ++s)
      av[rt][s] = pack_bf8(&h1b[(i0q + m16) * 128 + s * 32 + q * 8], ss);
    ss += __shfl_xor(ss, 16);
    ss += __shfl_xor(ss, 32);
    const float invrow = rsqrtf(ss + 0.01f);     // lane holds row i0q+m16
    #pragma unroll
    for (int r = 0; r < 4; ++r) invi[rt][r] = __shfl(invrow, q * 4 + r);
  }

  // staging geometry: thread -> row sr (0..127), cols scs..scs+31
  const int sr  = t >> 2;
  const int scs = (t & 3) * 32;
  const int xsw = (m16 & 7) << 4;                // K-read swizzle (row&7)<<4

  const f32x4 fz = {0.f, 0.f, 0.f, 0.f};
  float wpart[2][4] = {{0.f,0.f,0.f,0.f},{0.f,0.f,0.f,0.f}};
  float coef[2][4];

  // ---- 4 phases: pass1 h0, pass1 h1, pass2 h0, pass2 h1 ----
  for (int ph = 0; ph < 4; ++ph) {
    const int h = ph & 1;                        // K half: rows h*128..+127
    __syncthreads();                             // prior readers done / init
    {
      // stage K half h: all 512 threads; row sr, 32 cols from scs
      const float* p = h1b + (h * 128 + sr) * 128 + scs;
      float ss = 0.f;
      u32x4 w0 = pack_bf8(p, ss);
      u32x4 w1 = pack_bf8(p + 8, ss);
      u32x4 w2 = pack_bf8(p + 16, ss);
      u32x4 w3 = pack_bf8(p + 24, ss);
      ss += __shfl_xor(ss, 1);
      ss += __shfl_xor(ss, 2);
      char* kbB = (char*)KS + sr * 256;
      const int bb = scs * 2, xr = (sr & 7) << 4;
      *(u32x4*)(kbB + ((bb)      ^ xr)) = w0;
      *(u32x4*)(kbB + ((bb + 16) ^ xr)) = w1;
      *(u32x4*)(kbB + ((bb + 32) ^ xr)) = w2;
      *(u32x4*)(kbB + ((bb + 48) ^ xr)) = w3;
      if ((t & 3) == 0) {
        const float m = MK[h * 128 + sr];
        const float inv = rsqrtf(ss + 0.01f);
        SCL[sr] = (m > 0.f) ? inv : 0.f;
        SBS[sr] = (m > 0.f) ? 0.f : -1e38f;
      }
    }
    __syncthreads();                             // staged data visible

    // ---- 4 tiles, barrier-free ----
    for (int tl = 0; tl < 4; ++tl) {
      f32x4 Sa[2] = {fz, fz}, Sb[2] = {fz, fz};
      const char* kbB = (const char*)KS;
      const int rowA = (tl * 32 + m16) * 256;
      const int rowB = (tl * 32 + 16 + m16) * 256;
      #pragma unroll
      for (int s = 0; s < 4; ++s) {
        const int co = (s * 64 + q * 16) ^ xsw;  // (16+m16)&7 == m16&7
        const bf16x8 ba = *(const bf16x8*)(kbB + rowA + co);
        const bf16x8 bb = *(const bf16x8*)(kbB + rowB + co);
        const bf16x8 a0 = as_bf(av[0][s]);
        const bf16x8 a1 = as_bf(av[1][s]);
        Sa[0] = __builtin_amdgcn_mfma_f32_16x16x32_bf16(a0, ba, Sa[0], 0, 0, 0);
        Sb[0] = __builtin_amdgcn_mfma_f32_16x16x32_bf16(a0, bb, Sb[0], 0, 0, 0);
        Sa[1] = __builtin_amdgcn_mfma_f32_16x16x32_bf16(a1, ba, Sa[1], 0, 0, 0);
        Sb[1] = __builtin_amdgcn_mfma_f32_16x16x32_bf16(a1, bb, Sb[1], 0, 0, 0);
      }
      const float sA = SCL[tl * 32 + m16],      bA = SBS[tl * 32 + m16];
      const float sB = SCL[tl * 32 + 16 + m16], bB = SBS[tl * 32 + 16 + m16];
      if (ph < 2) {
        // pass 1: wsum partials (masked j -> exp(-1e38)=0)
        #pragma unroll
        for (int rt = 0; rt < 2; ++rt)
          #pragma unroll
          for (int r = 0; r < 4; ++r) {
            wpart[rt][r] += __expf(fmaf(Sa[rt][r] * invi[rt][r], sA, bA))
                          + __expf(fmaf(Sb[rt][r] * invi[rt][r], sB, bB));
          }
      } else {
        // pass 2: c[j] += coef_i * w_ij
        float cA = 0.f, cB = 0.f;
        #pragma unroll
        for (int rt = 0; rt < 2; ++rt)
          #pragma unroll
          for (int r = 0; r < 4; ++r) {
            cA += coef[rt][r] * __expf(fmaf(Sa[rt][r] * invi[rt][r], sA, bA));
            cB += coef[rt][r] * __expf(fmaf(Sb[rt][r] * invi[rt][r], sB, bB));
          }
        cA += __shfl_xor(cA, 16); cA += __shfl_xor(cA, 32);
        cB += __shfl_xor(cB, 16); cB += __shfl_xor(cB, 32);
        if (q == 0) {
          atomicAdd(&CJ[h * 128 + tl * 32 + m16], cA);
          atomicAdd(&CJ[h * 128 + tl * 32 + 16 + m16], cB);
        }
      }
    }

    if (ph == 1) {
      // wsum complete -> coef[rt][r] = LM[i] / wsum[i]
      #pragma unroll
      for (int rt = 0; rt < 2; ++rt)
        #pragma unroll
        for (int r = 0; r < 4; ++r) {
          float s = wpart[rt][r];
          s += __shfl_xor(s, 1); s += __shfl_xor(s, 2);
          s += __shfl_xor(s, 4); s += __shfl_xor(s, 8);
          coef[rt][r] = LM[wv * 32 + rt * 16 + q * 4 + r] / s;
        }
    }
  }
  __syncthreads();                               // pass2 atomics done

  // ---- cfull[j] = m[j]*c[j] + LM[j] (residual folded) ----
  if (t < 256) CJ[t] = MK[t] * CJ[t] + LM[t];
  __syncthreads();

  // ---- pooled sweep: HL[d] = sum_j cfull[j]*h1[j,d] ----
  {
    const int g = t >> 7, dd = t & 127;          // 4 groups x 64 rows
    float p = 0.f;
    #pragma unroll 8
    for (int n = 0; n < 64; ++n)
      p += CJ[g * 64 + n] * h1b[(g * 64 + n) * 128 + dd];
    PSC[g * 132 + dd] = p;
  }
  __syncthreads();
  if (t < 128)
    HLacc[t] = PSC[t] + PSC[132 + t] + PSC[264 + t] + PSC[396 + t];
  __syncthreads();

  // ---- cross cosine attention over h2 (single pass) ----
  if (t < 64) {
    float s = HLacc[t] * HLacc[t] + HLacc[t + 64] * HLacc[t + 64];
    s += __shfl_xor(s, 1); s += __shfl_xor(s, 2); s += __shfl_xor(s, 4);
    s += __shfl_xor(s, 8); s += __shfl_xor(s, 16); s += __shfl_xor(s, 32);
    if (t == 0) SC[0] = rsqrtf(s + 0.01f);
  }
  if (t < 256) MK[t] = (seq1[b * 256 + t] != 0) ? 1.f : 0.f;
  __syncthreads();

  const float* h2b = h2g + (size_t)b * 32768;
  {
    const int row8 = lane >> 3;          // 0..7
    const int sub  = lane & 7;           // 8 lanes/row, 16 f32 each
    const int slot = wv * 8 + row8;      // 0..63
    const float invq = SC[0];
    f32x4 acc4[4];
    #pragma unroll
    for (int c = 0; c < 4; ++c) acc4[c] = {0.f, 0.f, 0.f, 0.f};
    float ws2 = 0.f;
    const float* hl = &HLacc[sub * 4];
    #pragma unroll
    for (int kt = 0; kt < 4; ++kt) {
      const int k = kt * 64 + slot;
      const float* rowp = h2b + k * 128 + sub * 4;
      const float4 v0 = *(const float4*)(rowp);
      const float4 v1 = *(const float4*)(rowp + 32);
      const float4 v2 = *(const float4*)(rowp + 64);
      const float4 v3 = *(const float4*)(rowp + 96);
      float dot = v0.x*hl[0]  + v0.y*hl[1]  + v0.z*hl[2]  + v0.w*hl[3]
                + v1.x*hl[32] + v1.y*hl[33] + v1.z*hl[34] + v1.w*hl[35]
                + v2.x*hl[64] + v2.y*hl[65] + v2.z*hl[66] + v2.w*hl[67]
                + v3.x*hl[96] + v3.y*hl[97] + v3.z*hl[98] + v3.w*hl[99];
      float ss  = v0.x*v0.x + v0.y*v0.y + v0.z*v0.z + v0.w*v0.w
                + v1.x*v1.x + v1.y*v1.y + v1.z*v1.z + v1.w*v1.w
                + v2.x*v2.x + v2.y*v2.y + v2.z*v2.z + v2.w*v2.w
                + v3.x*v3.x + v3.y*v3.y + v3.z*v3.z + v3.w*v3.w;
      dot += __shfl_xor(dot, 1); dot += __shfl_xor(dot, 2); dot += __shfl_xor(dot, 4);
      ss  += __shfl_xor(ss, 1);  ss  += __shfl_xor(ss, 2);  ss  += __shfl_xor(ss, 4);
      const float w2 = __expf(dot * rsqrtf(ss + 0.01f) * invq) * MK[k];
      ws2 += w2;
      acc4[0][0] += w2*v0.x; acc4[0][1] += w2*v0.y; acc4[0][2] += w2*v0.z; acc4[0][3] += w2*v0.w;
      acc4[1][0] += w2*v1.x; acc4[1][1] += w2*v1.y; acc4[1][2] += w2*v1.z; acc4[1][3] += w2*v1.w;
      acc4[2][0] += w2*v2.x; acc4[2][1] += w2*v2.y; acc4[2][2] += w2*v2.z; acc4[2][3] += w2*v2.w;
      acc4[3][0] += w2*v3.x; acc4[3][1] += w2*v3.y; acc4[3][2] += w2*v3.z; acc4[3][3] += w2*v3.w;
    }
    #pragma unroll
    for (int c = 0; c < 4; ++c)
      *(f32x4*)&PSC[slot * 132 + c * 32 + sub * 4] = acc4[c];
    if (sub == 0) WS2[slot] = ws2;
  }
  __syncthreads();

  float hsum = 0.f;
  if (t < 128) {
    #pragma unroll
    for (int n = 0; n < 64; ++n) hsum += PSC[n * 132 + t];
  }
  if (t < 64) {
    float s = WS2[t];
    s += __shfl_xor(s, 1); s += __shfl_xor(s, 2); s += __shfl_xor(s, 4);
    s += __shfl_xor(s, 8); s += __shfl_xor(s, 16); s += __shfl_xor(s, 32);
    if (t == 0) SC[1] = s;
  }
  __syncthreads();
  if (t < 128) HH[t] = hsum / SC[1];
  __syncthreads();

  if (t < 128) {
    float o = 0.f;
    #pragma unroll 8
    for (int d = 0; d < 128; ++d)
      o += HH[d] * wg[d * 128 + t];
    outg[(size_t)b * 128 + t] = fmaxf(o, 0.f);
  }
}

extern "C" void kernel_launch(void* const* d_in, const int* in_sizes, int n_in,
                              void* d_out, int out_size, void* d_ws, size_t ws_size,
                              hipStream_t stream) {
  (void)in_sizes; (void)n_in; (void)d_ws; (void)ws_size; (void)out_size;
  const int*   seq     = (const int*)d_in[0];
  const int*   lastseq = (const int*)d_in[1];
  const int*   seq1    = (const int*)d_in[2];
  const float* h1      = (const float*)d_in[3];
  const float* h2      = (const float*)d_in[4];
  const float* w       = (const float*)d_in[5];
  float* out           = (float*)d_out;
  itd_fused<<<dim3(512), dim3(512), 0, stream>>>(seq, lastseq, seq1, h1, h2, w, out);
}